// Round 6
// baseline (868.981 us; speedup 1.0000x reference)
//
#include <hip/hip_runtime.h>
#include <hip/hip_bf16.h>
#include <stdint.h>

#if __has_builtin(__builtin_amdgcn_cvt_pk_f32_fp8) && __has_builtin(__builtin_amdgcn_cvt_pk_fp8_f32)
#define FP8_HW 1
#else
#define FP8_HW 0
#include <hip/hip_fp8.h>
#endif

#define N_NODES 100000
#define N_EDGES 1600000
#define FEAT 128

#define BKT_SHIFT 8
#define BKT_SIZE  256
#define NB_BKT    391          // ceil(N_NODES / 256)
#define BKT_CAP   5120         // mean 4092 + ceil4 pad ~384 + >10-sigma headroom

typedef uint16_t u16;
typedef uint32_t u32;
typedef __attribute__((ext_vector_type(8))) short bf16x8;
typedef __attribute__((ext_vector_type(4))) float f32x4;
typedef __attribute__((ext_vector_type(2))) float f32x2;

__device__ __forceinline__ u16 bf16_rn(float f){
  u32 u = __float_as_uint(f);
  u += 0x7FFFu + ((u >> 16) & 1u);
  return (u16)(u >> 16);
}
__device__ __forceinline__ float bf16_lo(u32 p){ return __uint_as_float(p << 16); }
__device__ __forceinline__ float bf16_hi(u32 p){ return __uint_as_float(p & 0xFFFF0000u); }

__device__ __forceinline__ void fp8x4_to_f32(u32 w, float* o){
#if FP8_HW
  f32x2 a = __builtin_amdgcn_cvt_pk_f32_fp8(w, false);
  f32x2 b = __builtin_amdgcn_cvt_pk_f32_fp8(w, true);
  o[0] = a.x; o[1] = a.y; o[2] = b.x; o[3] = b.y;
#else
  #pragma unroll
  for (int i = 0; i < 4; ++i){
    __hip_fp8_e4m3 t; t.__x = (uint8_t)((w >> (8 * i)) & 0xFF);
    o[i] = (float)t;
  }
#endif
}
__device__ __forceinline__ u32 f32x4_to_fp8(float a, float b, float c, float d){
#if FP8_HW
  u32 r = __builtin_amdgcn_cvt_pk_fp8_f32(a, b, 0, false);
  r = __builtin_amdgcn_cvt_pk_fp8_f32(c, d, r, true);
  return r;
#else
  __hip_fp8_e4m3 qa(a), qb(b), qc(c), qd(d);
  return (u32)qa.__x | ((u32)qb.__x << 8) | ((u32)qc.__x << 16) | ((u32)qd.__x << 24);
#endif
}

// ---------------- CSR build ----------------

// one edge per thread; slot via global atomic return. Max TLP for the random writes.
__global__ void bucket_scatter_kernel(const int* __restrict__ src, const int* __restrict__ dst,
                                      int* __restrict__ cursor, uint2* __restrict__ bbuf){
  int e = blockIdx.x * 256 + threadIdx.x;
  if (e >= N_EDGES) return;
  int d = dst[e];
  int b = d >> BKT_SHIFT;
  int p = atomicAdd(&cursor[b], 1);
  bbuf[(size_t)b * BKT_CAP + p] = make_uint2((u32)src[e], (u32)(d & (BKT_SIZE - 1)));
}

// one block (1024 thr, 16 waves) per bucket: per-node LDS hist + scan + LDS-atomic scatter.
// Per-node segments padded to multiples of 4 entries (agg reads uint4-aligned indices).
__global__ __launch_bounds__(1024) void csr_build_kernel(const uint2* __restrict__ bbuf,
                                 const int* __restrict__ cursor,
                                 int* __restrict__ offs, int* __restrict__ deg,
                                 float* __restrict__ inv_deg, int* __restrict__ eidx){
  __shared__ int hist[BKT_SIZE];
  __shared__ int s[BKT_SIZE];
  __shared__ int cu[BKT_SIZE];
  int b = blockIdx.x;
  int t = threadIdx.x;
  int lo = b * BKT_CAP;
  int hi = lo + cursor[b];
  if (t < BKT_SIZE) hist[t] = 0;
  __syncthreads();
  for (int e = lo + t; e < hi; e += 1024)
    atomicAdd(&hist[bbuf[e].y], 1);
  __syncthreads();
  int v = 0, pv = 0;
  if (t < BKT_SIZE){
    v  = hist[t];
    pv = (v + 3) & ~3;            // padded length
    s[t] = pv;
  }
  __syncthreads();
  for (int d = 1; d < BKT_SIZE; d <<= 1){
    int add = (t < BKT_SIZE && t >= d) ? s[t - d] : 0;
    __syncthreads();
    if (t < BKT_SIZE && t >= d) s[t] += add;
    __syncthreads();
  }
  if (t < BKT_SIZE){
    int excl = s[t] - pv;
    int node = b * BKT_SIZE + t;
    if (node < N_NODES){
      offs[node]    = lo + excl;
      deg[node]     = v;
      inv_deg[node] = 1.0f / fmaxf((float)v, 1.0f);
    }
    s[t]  = excl;
    cu[t] = 0;
  }
  __syncthreads();
  for (int e = lo + t; e < hi; e += 1024){
    uint2 q = bbuf[e];
    int p = atomicAdd(&cu[q.y], 1);
    eidx[lo + s[q.y] + p] = (int)q.x;
  }
}

// ---------------- conversions ----------------

__global__ void cvt_x8_kernel(const float* __restrict__ x, uint2* __restrict__ X8){
  int i = blockIdx.x * 256 + threadIdx.x;        // < 1.6M
  const float4* p = (const float4*)x + (size_t)i * 2;
  float4 a = p[0], b = p[1];
  uint2 o;
  o.x = f32x4_to_fp8(a.x, a.y, a.z, a.w);
  o.y = f32x4_to_fp8(b.x, b.y, b.z, b.w);
  X8[i] = o;
}

__global__ void cvt_h8_kernel(const u16* __restrict__ H, uint2* __restrict__ H8){
  int i = blockIdx.x * 256 + threadIdx.x;        // < 1.6M
  uint4 hq = ((const uint4*)H)[i];
  uint2 o;
  o.x = f32x4_to_fp8(bf16_lo(hq.x), bf16_hi(hq.x), bf16_lo(hq.y), bf16_hi(hq.y));
  o.y = f32x4_to_fp8(bf16_lo(hq.z), bf16_hi(hq.z), bf16_lo(hq.w), bf16_hi(hq.w));
  H8[i] = o;
}

__global__ void wprep3_kernel(const float* __restrict__ W1, const float* __restrict__ W2,
                              const float* __restrict__ W3, u16* __restrict__ Wp1,
                              u16* __restrict__ Wp2, u16* __restrict__ Wp3){
  int which = blockIdx.x >> 6;
  int b     = blockIdx.x & 63;
  const float* W = (which == 0) ? W1 : (which == 1) ? W2 : W3;
  u16*        Wp = (which == 0) ? Wp1 : (which == 1) ? Wp2 : Wp3;
  int idx = b * 256 + threadIdx.x;              // 0..16383
  int j    = idx & 7;
  int lane = (idx >> 3) & 63;
  int t    = idx >> 9;
  int k0 = t & 3, n0 = t >> 2;
  int k = k0 * 32 + (lane >> 4) * 8 + j;
  int n = n0 * 16 + (lane & 15);
  Wp[idx] = bf16_rn(W[k * FEAT + n]);
}

// ---------------- aggregation: 4 nodes/wave, fp8 neighbors, no cross-lane reduce ----------------
template<int SM>
__global__ void agg16_kernel(const u32* __restrict__ n8,     // fp8 table, row = 32 u32
                             const u16* __restrict__ hb,     // bf16 self table (SM=0)
                             const float* __restrict__ xf,   // fp32 self table (SM=1)
                             const int* __restrict__ offs,
                             const int* __restrict__ deg,
                             const float* __restrict__ inv_deg,
                             const int* __restrict__ eidx,
                             u16* __restrict__ T){
  int wid   = (int)((blockIdx.x * 256u + threadIdx.x) >> 6);
  int lane  = threadIdx.x & 63;
  int nsub  = lane >> 4;
  int slice = lane & 15;
  int node  = wid * 4 + nsub;
  bool vn   = node < N_NODES;
  int nc    = vn ? node : 0;
  int start = offs[nc];
  int cnt   = vn ? deg[nc] : 0;
  const int* ep = eidx + start;            // 16-B aligned (padded CSR)

  float acc[8];
  #pragma unroll
  for (int j = 0; j < 8; ++j) acc[j] = 0.f;

  uint4 q = (cnt > 0) ? *(const uint4*)ep : make_uint4(0, 0, 0, 0);

  for (int e = 0; e < cnt; e += 4){
    uint4 qn = *(const uint4*)(ep + e + 4);   // prefetch (stays within bucket capacity)
    int i0 = (int)q.x, i1 = (int)q.y, i2 = (int)q.z, i3 = (int)q.w;
    float f0 = 1.f;
    float f1 = (e + 1 < cnt) ? 1.f : 0.f; if (e + 1 >= cnt) i1 = 0;
    float f2 = (e + 2 < cnt) ? 1.f : 0.f; if (e + 2 >= cnt) i2 = 0;
    float f3 = (e + 3 < cnt) ? 1.f : 0.f; if (e + 3 >= cnt) i3 = 0;
    uint2 r0 = *(const uint2*)(n8 + (size_t)i0 * 32 + slice * 2);
    uint2 r1 = *(const uint2*)(n8 + (size_t)i1 * 32 + slice * 2);
    uint2 r2 = *(const uint2*)(n8 + (size_t)i2 * 32 + slice * 2);
    uint2 r3 = *(const uint2*)(n8 + (size_t)i3 * 32 + slice * 2);
    float t0[4], t1[4];
    fp8x4_to_f32(r0.x, t0); fp8x4_to_f32(r0.y, t1);
    acc[0]+=f0*t0[0]; acc[1]+=f0*t0[1]; acc[2]+=f0*t0[2]; acc[3]+=f0*t0[3];
    acc[4]+=f0*t1[0]; acc[5]+=f0*t1[1]; acc[6]+=f0*t1[2]; acc[7]+=f0*t1[3];
    fp8x4_to_f32(r1.x, t0); fp8x4_to_f32(r1.y, t1);
    acc[0]+=f1*t0[0]; acc[1]+=f1*t0[1]; acc[2]+=f1*t0[2]; acc[3]+=f1*t0[3];
    acc[4]+=f1*t1[0]; acc[5]+=f1*t1[1]; acc[6]+=f1*t1[2]; acc[7]+=f1*t1[3];
    fp8x4_to_f32(r2.x, t0); fp8x4_to_f32(r2.y, t1);
    acc[0]+=f2*t0[0]; acc[1]+=f2*t0[1]; acc[2]+=f2*t0[2]; acc[3]+=f2*t0[3];
    acc[4]+=f2*t1[0]; acc[5]+=f2*t1[1]; acc[6]+=f2*t1[2]; acc[7]+=f2*t1[3];
    fp8x4_to_f32(r3.x, t0); fp8x4_to_f32(r3.y, t1);
    acc[0]+=f3*t0[0]; acc[1]+=f3*t0[1]; acc[2]+=f3*t0[2]; acc[3]+=f3*t0[3];
    acc[4]+=f3*t1[0]; acc[5]+=f3*t1[1]; acc[6]+=f3*t1[2]; acc[7]+=f3*t1[3];
    q = qn;
  }

  if (!vn) return;
  float w = inv_deg[node];
  float self[8];
  if (SM == 1){
    const float* sp = xf + (size_t)node * FEAT + slice * 8;
    float4 a = *(const float4*)sp;
    float4 b = *(const float4*)(sp + 4);
    self[0]=a.x; self[1]=a.y; self[2]=a.z; self[3]=a.w;
    self[4]=b.x; self[5]=b.y; self[6]=b.z; self[7]=b.w;
  } else {
    const u16* sp = hb + (size_t)node * FEAT + slice * 8;
    uint4 s0 = *(const uint4*)sp;
    self[0]=bf16_lo(s0.x); self[1]=bf16_hi(s0.x); self[2]=bf16_lo(s0.y); self[3]=bf16_hi(s0.y);
    self[4]=bf16_lo(s0.z); self[5]=bf16_hi(s0.z); self[6]=bf16_lo(s0.w); self[7]=bf16_hi(s0.w);
  }
  uint4 o;
  o.x = (u32)bf16_rn(self[0] + w*acc[0]) | ((u32)bf16_rn(self[1] + w*acc[1]) << 16);
  o.y = (u32)bf16_rn(self[2] + w*acc[2]) | ((u32)bf16_rn(self[3] + w*acc[3]) << 16);
  o.z = (u32)bf16_rn(self[4] + w*acc[4]) | ((u32)bf16_rn(self[5] + w*acc[5]) << 16);
  o.w = (u32)bf16_rn(self[6] + w*acc[6]) | ((u32)bf16_rn(self[7] + w*acc[7]) << 16);
  *(uint4*)(T + (size_t)node * FEAT + slice * 8) = o;
}

// ---------------- GEMM: 32 rows/wave (2 tiles share B fragments), 128 rows/block ----------------
template<int MODE>   // 0: bf16 + relu; 1: fp32, no relu
__global__ __launch_bounds__(256) void gemm2_kernel(const u16* __restrict__ T,
                                                    const u16* __restrict__ Wp,
                                                    const float* __restrict__ bias,
                                                    void* __restrict__ out){
  int wave = threadIdx.x >> 6;
  int lane = threadIdx.x & 63;
  int row0 = blockIdx.x * 128 + wave * 32;
  if (row0 >= N_NODES) return;
  int quad = lane >> 4;
  int c    = lane & 15;

  f32x4 acc[2][8];
  #pragma unroll
  for (int t = 0; t < 2; ++t)
    #pragma unroll
    for (int i = 0; i < 8; ++i) acc[t][i] = (f32x4){0.f, 0.f, 0.f, 0.f};

  bf16x8 A[2][4];
  const u16* ar0 = T + (size_t)(row0 + c) * FEAT + quad * 8;
  const u16* ar1 = ar0 + 16 * FEAT;
  #pragma unroll
  for (int k0 = 0; k0 < 4; ++k0){
    A[0][k0] = *(const bf16x8*)(ar0 + k0 * 32);
    A[1][k0] = *(const bf16x8*)(ar1 + k0 * 32);
  }

  #pragma unroll
  for (int n0 = 0; n0 < 8; ++n0){
    #pragma unroll
    for (int k0 = 0; k0 < 4; ++k0){
      bf16x8 b = *(const bf16x8*)(Wp + (((n0 << 2) | k0) * 64 + lane) * 8);
      acc[0][n0] = __builtin_amdgcn_mfma_f32_16x16x32_bf16(A[0][k0], b, acc[0][n0], 0, 0, 0);
      acc[1][n0] = __builtin_amdgcn_mfma_f32_16x16x32_bf16(A[1][k0], b, acc[1][n0], 0, 0, 0);
    }
  }

  #pragma unroll
  for (int t = 0; t < 2; ++t){
    #pragma unroll
    for (int n0 = 0; n0 < 8; ++n0){
      float bv = bias[n0 * 16 + c];
      #pragma unroll
      for (int r = 0; r < 4; ++r){
        int row = row0 + t * 16 + quad * 4 + r;
        int col = n0 * 16 + c;
        float v = acc[t][n0][r] + bv;
        if (MODE == 0){
          v = fmaxf(v, 0.f);
          ((u16*)out)[(size_t)row * FEAT + col] = bf16_rn(v);
        } else {
          ((float*)out)[(size_t)row * FEAT + col] = v;
        }
      }
    }
  }
}

// ---------------- launch ----------------

static inline size_t align_up(size_t x){ return (x + 255) & ~(size_t)255; }

extern "C" void kernel_launch(void* const* d_in, const int* in_sizes, int n_in,
                              void* d_out, int out_size, void* d_ws, size_t ws_size,
                              hipStream_t stream){
  const float* x  = (const float*)d_in[0];
  const float* W1 = (const float*)d_in[1];
  const float* b1 = (const float*)d_in[2];
  const float* W2 = (const float*)d_in[3];
  const float* b2 = (const float*)d_in[4];
  const float* W3 = (const float*)d_in[5];
  const float* b3 = (const float*)d_in[6];
  const int* esrc = (const int*)d_in[7];
  const int* edst = (const int*)d_in[8];

  char* w = (char*)d_ws;
  int*   cursor  = (int*)w;    w += align_up((size_t)NB_BKT * 4);
  int*   deg     = (int*)w;    w += align_up((size_t)N_NODES * 4);
  int*   offs    = (int*)w;    w += align_up((size_t)N_NODES * 4);
  float* inv_deg = (float*)w;  w += align_up((size_t)N_NODES * 4);
  int*   eidx    = (int*)w;    w += align_up((size_t)NB_BKT * BKT_CAP * 4);  // 8 MB padded CSR
  u16*   Wp1     = (u16*)w;    w += align_up((size_t)16384 * 2);
  u16*   Wp2     = (u16*)w;    w += align_up((size_t)16384 * 2);
  u16*   Wp3     = (u16*)w;    w += align_up((size_t)16384 * 2);
  u16*   T       = (u16*)w;    w += align_up((size_t)N_NODES * FEAT * 2);    // 25.6 MB

  // bucket buffer (16 MB) aliases T — T is dead during CSR build
  uint2* bbuf = (uint2*)T;

  // d_out (51.2 MB) hosts: H bf16 [0,25.6) | H8 fp8 [25.6,38.4) | X8 fp8 [38.4,51.2)
  u16* H  = (u16*)d_out;
  u32* H8 = (u32*)((char*)d_out + (size_t)N_NODES * FEAT * 2);
  u32* X8 = (u32*)((char*)d_out + (size_t)N_NODES * FEAT * 3);

  hipMemsetAsync(cursor, 0, (size_t)NB_BKT * 4, stream);

  bucket_scatter_kernel<<<(N_EDGES + 255) / 256, 256, 0, stream>>>(esrc, edst, cursor, bbuf);
  csr_build_kernel<<<NB_BKT, 1024, 0, stream>>>(bbuf, cursor, offs, deg, inv_deg, eidx);

  wprep3_kernel<<<192, 256, 0, stream>>>(W1, W2, W3, Wp1, Wp2, Wp3);
  cvt_x8_kernel<<<N_EDGES / 256, 256, 0, stream>>>(x, (uint2*)X8);

  const int AGG_BLOCKS  = (N_NODES + 15) / 16;        // 4 nodes/wave, 4 waves/block
  const int GEMM_BLOCKS = (N_NODES + 127) / 128;
  const int CVT_BLOCKS  = N_EDGES / 256;

  // layer 1: neighbors X8, self fp32 x -> T -> H
  agg16_kernel<1><<<AGG_BLOCKS, 256, 0, stream>>>(X8, (const u16*)nullptr, x,
                                                  offs, deg, inv_deg, eidx, T);
  gemm2_kernel<0><<<GEMM_BLOCKS, 256, 0, stream>>>(T, Wp1, b1, H);

  // layer 2
  cvt_h8_kernel<<<CVT_BLOCKS, 256, 0, stream>>>(H, (uint2*)H8);
  agg16_kernel<0><<<AGG_BLOCKS, 256, 0, stream>>>(H8, H, (const float*)nullptr,
                                                  offs, deg, inv_deg, eidx, T);
  gemm2_kernel<0><<<GEMM_BLOCKS, 256, 0, stream>>>(T, Wp2, b2, H);

  // layer 3
  cvt_h8_kernel<<<CVT_BLOCKS, 256, 0, stream>>>(H, (uint2*)H8);
  agg16_kernel<0><<<AGG_BLOCKS, 256, 0, stream>>>(H8, H, (const float*)nullptr,
                                                  offs, deg, inv_deg, eidx, T);
  gemm2_kernel<1><<<GEMM_BLOCKS, 256, 0, stream>>>(T, Wp3, b3, d_out);

  (void)in_sizes; (void)n_in; (void)out_size; (void)ws_size; (void)w;
}

// Round 7
// 336.724 us; speedup vs baseline: 2.5807x; 2.5807x over previous
//
#include <hip/hip_runtime.h>
#include <hip/hip_bf16.h>
#include <stdint.h>

#if __has_builtin(__builtin_amdgcn_cvt_pk_f32_fp8) && __has_builtin(__builtin_amdgcn_cvt_pk_fp8_f32)
#define FP8_HW 1
#else
#define FP8_HW 0
#include <hip/hip_fp8.h>
#endif

#define N_NODES 100000
#define N_EDGES 1600000
#define FEAT 128

#define BKT_SHIFT 8
#define BKT_SIZE  256
#define NB_BKT    391          // ceil(N_NODES / 256)
#define BKT_CAP   5120         // mean 4092 + ceil4 pad ~384 + >9-sigma headroom
#define NB_SC     800          // blocks in edge passes
#define EPB_SC    2000         // edges per block (800*2000 = 1.6M exactly)

typedef uint16_t u16;
typedef uint32_t u32;
typedef __attribute__((ext_vector_type(8))) short bf16x8;
typedef __attribute__((ext_vector_type(4))) float f32x4;
typedef __attribute__((ext_vector_type(2))) float f32x2;

__device__ __forceinline__ u16 bf16_rn(float f){
  u32 u = __float_as_uint(f);
  u += 0x7FFFu + ((u >> 16) & 1u);
  return (u16)(u >> 16);
}
__device__ __forceinline__ float bf16_lo(u32 p){ return __uint_as_float(p << 16); }
__device__ __forceinline__ float bf16_hi(u32 p){ return __uint_as_float(p & 0xFFFF0000u); }

__device__ __forceinline__ void fp8x4_to_f32(u32 w, float* o){
#if FP8_HW
  f32x2 a = __builtin_amdgcn_cvt_pk_f32_fp8(w, false);
  f32x2 b = __builtin_amdgcn_cvt_pk_f32_fp8(w, true);
  o[0] = a.x; o[1] = a.y; o[2] = b.x; o[3] = b.y;
#else
  #pragma unroll
  for (int i = 0; i < 4; ++i){
    __hip_fp8_e4m3 t; t.__x = (uint8_t)((w >> (8 * i)) & 0xFF);
    o[i] = (float)t;
  }
#endif
}
__device__ __forceinline__ u32 f32x4_to_fp8(float a, float b, float c, float d){
#if FP8_HW
  u32 r = __builtin_amdgcn_cvt_pk_fp8_f32(a, b, 0, false);
  r = __builtin_amdgcn_cvt_pk_fp8_f32(c, d, r, true);
  return r;
#else
  __hip_fp8_e4m3 qa(a), qb(b), qc(c), qd(d);
  return (u32)qa.__x | ((u32)qb.__x << 8) | ((u32)qc.__x << 16) | ((u32)qd.__x << 24);
#endif
}

// ---------------- CSR build: atomic-free deterministic bucket sort ----------------

// Phase A: per-block LDS histogram -> hcnt[block][bucket]
__global__ __launch_bounds__(512) void hist_kernel(const int* __restrict__ dst,
                                                   int* __restrict__ hcnt){
  __shared__ int h[NB_BKT];
  for (int i = threadIdx.x; i < NB_BKT; i += 512) h[i] = 0;
  __syncthreads();
  int base = blockIdx.x * EPB_SC;
  for (int e = base + threadIdx.x; e < base + EPB_SC; e += 512)
    atomicAdd(&h[dst[e] >> BKT_SHIFT], 1);
  __syncthreads();
  for (int i = threadIdx.x; i < NB_BKT; i += 512)
    hcnt[blockIdx.x * NB_BKT + i] = h[i];
}

// Phase B: per-bucket exclusive scan over blocks; hcnt becomes absolute slot starts
__global__ void hscan_kernel(int* __restrict__ hcnt, int* __restrict__ cursor){
  __shared__ int s[256];
  int b = blockIdx.x, t = threadIdx.x;
  int v[4]; int sum = 0;
  #pragma unroll
  for (int j = 0; j < 4; ++j){
    int blk = 4 * t + j;
    v[j] = (blk < NB_SC) ? hcnt[blk * NB_BKT + b] : 0;
    sum += v[j];
  }
  s[t] = sum;
  __syncthreads();
  for (int d = 1; d < 256; d <<= 1){
    int add = (t >= d) ? s[t - d] : 0;
    __syncthreads();
    s[t] += add;
    __syncthreads();
  }
  int excl = s[t] - sum;
  #pragma unroll
  for (int j = 0; j < 4; ++j){
    int blk = 4 * t + j;
    if (blk < NB_SC){ hcnt[blk * NB_BKT + b] = excl; excl += v[j]; }
  }
  if (t == 255) cursor[b] = s[255];
}

// Phase C: scatter with LDS cursors initialized from hcnt — zero global atomics
__global__ __launch_bounds__(512) void scatter_kernel(const int* __restrict__ src,
                                                      const int* __restrict__ dst,
                                                      const int* __restrict__ hcnt,
                                                      uint2* __restrict__ bbuf){
  __shared__ int cur[NB_BKT];
  for (int i = threadIdx.x; i < NB_BKT; i += 512)
    cur[i] = hcnt[blockIdx.x * NB_BKT + i];
  __syncthreads();
  int base = blockIdx.x * EPB_SC;
  for (int e = base + threadIdx.x; e < base + EPB_SC; e += 512){
    int d = dst[e];
    int b = d >> BKT_SHIFT;
    int p = atomicAdd(&cur[b], 1);
    bbuf[(size_t)b * BKT_CAP + p] = make_uint2((u32)src[e], (u32)(d & (BKT_SIZE - 1)));
  }
}

// one block (1024 thr) per bucket: per-node LDS hist + scan + LDS-atomic scatter.
// Per-node segments padded to multiples of 4 entries (agg reads uint4-aligned indices).
__global__ __launch_bounds__(1024) void csr_build_kernel(const uint2* __restrict__ bbuf,
                                 const int* __restrict__ cursor,
                                 int* __restrict__ offs, int* __restrict__ deg,
                                 float* __restrict__ inv_deg, int* __restrict__ eidx){
  __shared__ int hist[BKT_SIZE];
  __shared__ int s[BKT_SIZE];
  __shared__ int cu[BKT_SIZE];
  int b = blockIdx.x;
  int t = threadIdx.x;
  int lo = b * BKT_CAP;
  int hi = lo + cursor[b];
  if (t < BKT_SIZE) hist[t] = 0;
  __syncthreads();
  for (int e = lo + t; e < hi; e += 1024)
    atomicAdd(&hist[bbuf[e].y], 1);
  __syncthreads();
  int v = 0, pv = 0;
  if (t < BKT_SIZE){
    v  = hist[t];
    pv = (v + 3) & ~3;            // padded length
    s[t] = pv;
  }
  __syncthreads();
  for (int d = 1; d < BKT_SIZE; d <<= 1){
    int add = (t < BKT_SIZE && t >= d) ? s[t - d] : 0;
    __syncthreads();
    if (t < BKT_SIZE && t >= d) s[t] += add;
    __syncthreads();
  }
  if (t < BKT_SIZE){
    int excl = s[t] - pv;
    int node = b * BKT_SIZE + t;
    if (node < N_NODES){
      offs[node]    = lo + excl;
      deg[node]     = v;
      inv_deg[node] = 1.0f / fmaxf((float)v, 1.0f);
    }
    s[t]  = excl;
    cu[t] = 0;
  }
  __syncthreads();
  for (int e = lo + t; e < hi; e += 1024){
    uint2 q = bbuf[e];
    int p = atomicAdd(&cu[q.y], 1);
    eidx[lo + s[q.y] + p] = (int)q.x;
  }
}

// ---------------- conversions ----------------

__global__ void cvt_x8_kernel(const float* __restrict__ x, uint2* __restrict__ X8){
  int i = blockIdx.x * 256 + threadIdx.x;        // < 1.6M
  const float4* p = (const float4*)x + (size_t)i * 2;
  float4 a = p[0], b = p[1];
  uint2 o;
  o.x = f32x4_to_fp8(a.x, a.y, a.z, a.w);
  o.y = f32x4_to_fp8(b.x, b.y, b.z, b.w);
  X8[i] = o;
}

__global__ void cvt_h8_kernel(const u16* __restrict__ H, uint2* __restrict__ H8){
  int i = blockIdx.x * 256 + threadIdx.x;        // < 1.6M
  uint4 hq = ((const uint4*)H)[i];
  uint2 o;
  o.x = f32x4_to_fp8(bf16_lo(hq.x), bf16_hi(hq.x), bf16_lo(hq.y), bf16_hi(hq.y));
  o.y = f32x4_to_fp8(bf16_lo(hq.z), bf16_hi(hq.z), bf16_lo(hq.w), bf16_hi(hq.w));
  H8[i] = o;
}

__global__ void wprep3_kernel(const float* __restrict__ W1, const float* __restrict__ W2,
                              const float* __restrict__ W3, u16* __restrict__ Wp1,
                              u16* __restrict__ Wp2, u16* __restrict__ Wp3){
  int which = blockIdx.x >> 6;
  int b     = blockIdx.x & 63;
  const float* W = (which == 0) ? W1 : (which == 1) ? W2 : W3;
  u16*        Wp = (which == 0) ? Wp1 : (which == 1) ? Wp2 : Wp3;
  int idx = b * 256 + threadIdx.x;              // 0..16383
  int j    = idx & 7;
  int lane = (idx >> 3) & 63;
  int t    = idx >> 9;
  int k0 = t & 3, n0 = t >> 2;
  int k = k0 * 32 + (lane >> 4) * 8 + j;
  int n = n0 * 16 + (lane & 15);
  Wp[idx] = bf16_rn(W[k * FEAT + n]);
}

// ---------------- aggregation: 4 nodes/wave, fp8 neighbors, no cross-lane reduce ----------------
template<int SM>
__global__ void agg16_kernel(const u32* __restrict__ n8,     // fp8 table, row = 32 u32
                             const u16* __restrict__ hb,     // bf16 self table (SM=0)
                             const float* __restrict__ xf,   // fp32 self table (SM=1)
                             const int* __restrict__ offs,
                             const int* __restrict__ deg,
                             const float* __restrict__ inv_deg,
                             const int* __restrict__ eidx,
                             u16* __restrict__ T){
  int wid   = (int)((blockIdx.x * 256u + threadIdx.x) >> 6);
  int lane  = threadIdx.x & 63;
  int nsub  = lane >> 4;
  int slice = lane & 15;
  int node  = wid * 4 + nsub;
  bool vn   = node < N_NODES;
  int nc    = vn ? node : 0;
  int start = offs[nc];
  int cnt   = vn ? deg[nc] : 0;
  const int* ep = eidx + start;            // 16-B aligned (padded CSR)

  float acc[8];
  #pragma unroll
  for (int j = 0; j < 8; ++j) acc[j] = 0.f;

  uint4 q = (cnt > 0) ? *(const uint4*)ep : make_uint4(0, 0, 0, 0);

  for (int e = 0; e < cnt; e += 4){
    uint4 qn = *(const uint4*)(ep + e + 4);   // prefetch (stays within bucket capacity)
    int i0 = (int)q.x, i1 = (int)q.y, i2 = (int)q.z, i3 = (int)q.w;
    float f0 = 1.f;
    float f1 = (e + 1 < cnt) ? 1.f : 0.f; if (e + 1 >= cnt) i1 = 0;
    float f2 = (e + 2 < cnt) ? 1.f : 0.f; if (e + 2 >= cnt) i2 = 0;
    float f3 = (e + 3 < cnt) ? 1.f : 0.f; if (e + 3 >= cnt) i3 = 0;
    uint2 r0 = *(const uint2*)(n8 + (size_t)i0 * 32 + slice * 2);
    uint2 r1 = *(const uint2*)(n8 + (size_t)i1 * 32 + slice * 2);
    uint2 r2 = *(const uint2*)(n8 + (size_t)i2 * 32 + slice * 2);
    uint2 r3 = *(const uint2*)(n8 + (size_t)i3 * 32 + slice * 2);
    float t0[4], t1[4];
    fp8x4_to_f32(r0.x, t0); fp8x4_to_f32(r0.y, t1);
    acc[0]+=f0*t0[0]; acc[1]+=f0*t0[1]; acc[2]+=f0*t0[2]; acc[3]+=f0*t0[3];
    acc[4]+=f0*t1[0]; acc[5]+=f0*t1[1]; acc[6]+=f0*t1[2]; acc[7]+=f0*t1[3];
    fp8x4_to_f32(r1.x, t0); fp8x4_to_f32(r1.y, t1);
    acc[0]+=f1*t0[0]; acc[1]+=f1*t0[1]; acc[2]+=f1*t0[2]; acc[3]+=f1*t0[3];
    acc[4]+=f1*t1[0]; acc[5]+=f1*t1[1]; acc[6]+=f1*t1[2]; acc[7]+=f1*t1[3];
    fp8x4_to_f32(r2.x, t0); fp8x4_to_f32(r2.y, t1);
    acc[0]+=f2*t0[0]; acc[1]+=f2*t0[1]; acc[2]+=f2*t0[2]; acc[3]+=f2*t0[3];
    acc[4]+=f2*t1[0]; acc[5]+=f2*t1[1]; acc[6]+=f2*t1[2]; acc[7]+=f2*t1[3];
    fp8x4_to_f32(r3.x, t0); fp8x4_to_f32(r3.y, t1);
    acc[0]+=f3*t0[0]; acc[1]+=f3*t0[1]; acc[2]+=f3*t0[2]; acc[3]+=f3*t0[3];
    acc[4]+=f3*t1[0]; acc[5]+=f3*t1[1]; acc[6]+=f3*t1[2]; acc[7]+=f3*t1[3];
    q = qn;
  }

  if (!vn) return;
  float w = inv_deg[node];
  float self[8];
  if (SM == 1){
    const float* sp = xf + (size_t)node * FEAT + slice * 8;
    float4 a = *(const float4*)sp;
    float4 b = *(const float4*)(sp + 4);
    self[0]=a.x; self[1]=a.y; self[2]=a.z; self[3]=a.w;
    self[4]=b.x; self[5]=b.y; self[6]=b.z; self[7]=b.w;
  } else {
    const u16* sp = hb + (size_t)node * FEAT + slice * 8;
    uint4 s0 = *(const uint4*)sp;
    self[0]=bf16_lo(s0.x); self[1]=bf16_hi(s0.x); self[2]=bf16_lo(s0.y); self[3]=bf16_hi(s0.y);
    self[4]=bf16_lo(s0.z); self[5]=bf16_hi(s0.z); self[6]=bf16_lo(s0.w); self[7]=bf16_hi(s0.w);
  }
  uint4 o;
  o.x = (u32)bf16_rn(self[0] + w*acc[0]) | ((u32)bf16_rn(self[1] + w*acc[1]) << 16);
  o.y = (u32)bf16_rn(self[2] + w*acc[2]) | ((u32)bf16_rn(self[3] + w*acc[3]) << 16);
  o.z = (u32)bf16_rn(self[4] + w*acc[4]) | ((u32)bf16_rn(self[5] + w*acc[5]) << 16);
  o.w = (u32)bf16_rn(self[6] + w*acc[6]) | ((u32)bf16_rn(self[7] + w*acc[7]) << 16);
  *(uint4*)(T + (size_t)node * FEAT + slice * 8) = o;
}

// ---------------- GEMM: 32 rows/wave (2 tiles share B fragments), 128 rows/block ----------------
template<int MODE>   // 0: bf16 + relu; 1: fp32, no relu
__global__ __launch_bounds__(256) void gemm2_kernel(const u16* __restrict__ T,
                                                    const u16* __restrict__ Wp,
                                                    const float* __restrict__ bias,
                                                    void* __restrict__ out){
  int wave = threadIdx.x >> 6;
  int lane = threadIdx.x & 63;
  int row0 = blockIdx.x * 128 + wave * 32;
  if (row0 >= N_NODES) return;
  int quad = lane >> 4;
  int c    = lane & 15;

  f32x4 acc[2][8];
  #pragma unroll
  for (int t = 0; t < 2; ++t)
    #pragma unroll
    for (int i = 0; i < 8; ++i) acc[t][i] = (f32x4){0.f, 0.f, 0.f, 0.f};

  bf16x8 A[2][4];
  const u16* ar0 = T + (size_t)(row0 + c) * FEAT + quad * 8;
  const u16* ar1 = ar0 + 16 * FEAT;
  #pragma unroll
  for (int k0 = 0; k0 < 4; ++k0){
    A[0][k0] = *(const bf16x8*)(ar0 + k0 * 32);
    A[1][k0] = *(const bf16x8*)(ar1 + k0 * 32);
  }

  #pragma unroll
  for (int n0 = 0; n0 < 8; ++n0){
    #pragma unroll
    for (int k0 = 0; k0 < 4; ++k0){
      bf16x8 b = *(const bf16x8*)(Wp + (((n0 << 2) | k0) * 64 + lane) * 8);
      acc[0][n0] = __builtin_amdgcn_mfma_f32_16x16x32_bf16(A[0][k0], b, acc[0][n0], 0, 0, 0);
      acc[1][n0] = __builtin_amdgcn_mfma_f32_16x16x32_bf16(A[1][k0], b, acc[1][n0], 0, 0, 0);
    }
  }

  #pragma unroll
  for (int t = 0; t < 2; ++t){
    #pragma unroll
    for (int n0 = 0; n0 < 8; ++n0){
      float bv = bias[n0 * 16 + c];
      #pragma unroll
      for (int r = 0; r < 4; ++r){
        int row = row0 + t * 16 + quad * 4 + r;
        int col = n0 * 16 + c;
        float v = acc[t][n0][r] + bv;
        if (MODE == 0){
          v = fmaxf(v, 0.f);
          ((u16*)out)[(size_t)row * FEAT + col] = bf16_rn(v);
        } else {
          ((float*)out)[(size_t)row * FEAT + col] = v;
        }
      }
    }
  }
}

// ---------------- launch ----------------

static inline size_t align_up(size_t x){ return (x + 255) & ~(size_t)255; }

extern "C" void kernel_launch(void* const* d_in, const int* in_sizes, int n_in,
                              void* d_out, int out_size, void* d_ws, size_t ws_size,
                              hipStream_t stream){
  const float* x  = (const float*)d_in[0];
  const float* W1 = (const float*)d_in[1];
  const float* b1 = (const float*)d_in[2];
  const float* W2 = (const float*)d_in[3];
  const float* b2 = (const float*)d_in[4];
  const float* W3 = (const float*)d_in[5];
  const float* b3 = (const float*)d_in[6];
  const int* esrc = (const int*)d_in[7];
  const int* edst = (const int*)d_in[8];

  char* w = (char*)d_ws;
  int*   cursor  = (int*)w;    w += align_up((size_t)NB_BKT * 4);
  int*   hcnt    = (int*)w;    w += align_up((size_t)NB_SC * NB_BKT * 4);    // 1.25 MB
  int*   deg     = (int*)w;    w += align_up((size_t)N_NODES * 4);
  int*   offs    = (int*)w;    w += align_up((size_t)N_NODES * 4);
  float* inv_deg = (float*)w;  w += align_up((size_t)N_NODES * 4);
  int*   eidx    = (int*)w;    w += align_up((size_t)NB_BKT * BKT_CAP * 4);  // 8 MB padded CSR
  u16*   Wp1     = (u16*)w;    w += align_up((size_t)16384 * 2);
  u16*   Wp2     = (u16*)w;    w += align_up((size_t)16384 * 2);
  u16*   Wp3     = (u16*)w;    w += align_up((size_t)16384 * 2);
  u16*   T       = (u16*)w;    w += align_up((size_t)N_NODES * FEAT * 2);    // 25.6 MB

  // bucket buffer (16 MB) aliases T — T is dead during CSR build
  uint2* bbuf = (uint2*)T;

  // d_out (51.2 MB) hosts: H bf16 [0,25.6) | H8 fp8 [25.6,38.4) | X8 fp8 [38.4,51.2)
  u16* H  = (u16*)d_out;
  u32* H8 = (u32*)((char*)d_out + (size_t)N_NODES * FEAT * 2);
  u32* X8 = (u32*)((char*)d_out + (size_t)N_NODES * FEAT * 3);

  // CSR build: atomic-free deterministic counting sort
  hist_kernel<<<NB_SC, 512, 0, stream>>>(edst, hcnt);
  hscan_kernel<<<NB_BKT, 256, 0, stream>>>(hcnt, cursor);
  scatter_kernel<<<NB_SC, 512, 0, stream>>>(esrc, edst, hcnt, bbuf);
  csr_build_kernel<<<NB_BKT, 1024, 0, stream>>>(bbuf, cursor, offs, deg, inv_deg, eidx);

  wprep3_kernel<<<192, 256, 0, stream>>>(W1, W2, W3, Wp1, Wp2, Wp3);
  cvt_x8_kernel<<<N_EDGES / 256, 256, 0, stream>>>(x, (uint2*)X8);

  const int AGG_BLOCKS  = (N_NODES + 15) / 16;        // 4 nodes/wave, 4 waves/block
  const int GEMM_BLOCKS = (N_NODES + 127) / 128;
  const int CVT_BLOCKS  = N_EDGES / 256;

  // layer 1: neighbors X8, self fp32 x -> T -> H
  agg16_kernel<1><<<AGG_BLOCKS, 256, 0, stream>>>(X8, (const u16*)nullptr, x,
                                                  offs, deg, inv_deg, eidx, T);
  gemm2_kernel<0><<<GEMM_BLOCKS, 256, 0, stream>>>(T, Wp1, b1, H);

  // layer 2
  cvt_h8_kernel<<<CVT_BLOCKS, 256, 0, stream>>>(H, (uint2*)H8);
  agg16_kernel<0><<<AGG_BLOCKS, 256, 0, stream>>>(H8, H, (const float*)nullptr,
                                                  offs, deg, inv_deg, eidx, T);
  gemm2_kernel<0><<<GEMM_BLOCKS, 256, 0, stream>>>(T, Wp2, b2, H);

  // layer 3
  cvt_h8_kernel<<<CVT_BLOCKS, 256, 0, stream>>>(H, (uint2*)H8);
  agg16_kernel<0><<<AGG_BLOCKS, 256, 0, stream>>>(H8, H, (const float*)nullptr,
                                                  offs, deg, inv_deg, eidx, T);
  gemm2_kernel<1><<<GEMM_BLOCKS, 256, 0, stream>>>(T, Wp3, b3, d_out);

  (void)in_sizes; (void)n_in; (void)out_size; (void)ws_size; (void)w;
}